// Round 5
// baseline (180.872 us; speedup 1.0000x reference)
//
#include <hip/hip_runtime.h>
#include <math.h>

// VectorQuantizer: argmin_k ||x_n - c_k||^2, N=32768, K=8192, D=64, fp32.
// Round-11: round-10 geometry + the negative-dist key fix.
//
// Round-10 post-mortem (failed, absmax 8084): dropping xsq makes the dist
// surrogate d = csq - 2<x,c> often NEGATIVE; the u64 reduction compared raw
// float bits as unsigned, where negative IEEE patterns > positive -> the
// argmin reduction discarded every negative (i.e. best) candidate. Fix:
// monotone key map  u ^= ((int)u>>31) | 0x80000000  before packing (flips
// negatives, sign-sets positives -> unsigned order == float order). Exact;
// keeps lowest-code-on-tie semantics. Everything else unchanged from r10:
//  * 8-wave single block/CU (TPB=512), BROWS=128 -> 256 blocks = 1/CU.
//  * BTILE=128, codes partitioned: wave = (code-group cg, row-half rh);
//    each wave 64 rows x 32 codes = 24 MFMA per tile from one 8KB B-read.
//  * Per-CU-per-tile budgets (m119: 32x32x16 = ~8cy/CU): MFMA 1550cy wall,
//    LDS 64KB reads + 32KB DMA ~1150cy, VALU ~680cy -> MFMA-bound, 2 w/SIMD.
//  * Counted-vmcnt 3-buffer pipeline (proven r8/r9): 4x gload_lds16 (+1
//    gload_lds4 csq, waves 0-1) per tile; barrier = "s_waitcnt vmcnt(4)
//    lgkmcnt(0); s_barrier"; never drains mid-loop.
//  * A-split staged transiently in buffer-2 region; afr reads fenced by
//    lgkmcnt(0)+barrier before body 0's tile-2 DMA can overwrite it.
// Numerics identical in kind to rounds 7-9 (all passed, absmax 0): 2-plane
// f16 split (plane1 denormal-zeroed, plane2 pre-scaled 2^12), 3 products
// (accA=h1g1 4-chain, accB=h1g2'+h2'g1 8-chain), d = fmaf(-2,
// fmaf(accB,2^-12,accA), csq)  [xsq omitted: per-row constant, argmin-
// invariant], strict < ascending code, mapped-u64 mins = first-occurrence.
// C/D layout (measured m74/m101): col=lane&31, row=(reg&3)+8*(reg>>2)+4*(lane>>5).

typedef __attribute__((ext_vector_type(8)))  _Float16 h8v;
typedef __attribute__((ext_vector_type(16))) float f16v;

constexpr int NROWS = 32768;
constexpr int KC    = 8192;
constexpr int DD    = 64;
constexpr int TPB   = 512;                 // 8 waves: 4 code-groups x 2 row-halves
constexpr int PTPB  = 256;                 // pre-kernel block size
constexpr int BROWS = 128;                 // rows per block -> 256 blocks = 1/CU
constexpr int BTILE = 128;                 // codes per tile (4 x 32-code groups)
constexpr int NT    = KC / BTILE;          // 64 tiles
constexpr int TILE_HALFS = BTILE * DD * 2;     // 16384 halves = 32 KB per tile
constexpr int BUF_HALFS  = TILE_HALFS + 256;   // + 128-float csq slot (512 B)

__device__ __forceinline__ void split2h(float v, _Float16& h1, _Float16& h2) {
  const float av = fabsf(v);
  _Float16 a = (_Float16)v;                  // RNE
  if (av < 6.1035156e-5f) a = (_Float16)0.f; // keep plane-1 out of f16 denormals
  h1 = a;
  h2 = (_Float16)((v - (float)a) * 4096.f);  // exact residual, scaled 2^12
}

__device__ __forceinline__ void gload_lds16(const void* g, void* l) {
  __builtin_amdgcn_global_load_lds(
      (const __attribute__((address_space(1))) void*)g,
      (__attribute__((address_space(3))) void*)l, 16, 0, 0);
}
__device__ __forceinline__ void gload_lds4(const void* g, void* l) {
  __builtin_amdgcn_global_load_lds(
      (const __attribute__((address_space(1))) void*)g,
      (__attribute__((address_space(3))) void*)l, 4, 0, 0);
}

// Monotone map: unsigned order of mapped bits == float order (handles negatives).
__device__ __forceinline__ unsigned fkey(float f) {
  const unsigned u = __float_as_uint(f);
  return u ^ (((unsigned)((int)u >> 31)) | 0x80000000u);
}

// Pre-kernel (128 blocks, 4 threads/code): split cb -> frag-ordered bSwz
// (2 f16 planes) + csq. Unchanged from rounds 9/10.
__global__ void vq_pre_kernel(const float* __restrict__ cb,
                              _Float16* __restrict__ bSwz,
                              float* __restrict__ csq) {
  const int gidx = blockIdx.x * PTPB + threadIdx.x;  // 0..32767
  const int code = gidx >> 2;
  const int kc4  = gidx & 3;                         // this thread's k-chunk
  const float* cp = cb + (size_t)code * DD + kc4 * 16;
  float v[16];
#pragma unroll
  for (int d = 0; d < 16; d += 4) {
    const float4 g = *(const float4*)(cp + d);
    v[d] = g.x; v[d + 1] = g.y; v[d + 2] = g.z; v[d + 3] = g.w;
  }
  float s = 0.f;
#pragma unroll
  for (int d = 0; d < 16; ++d) s = fmaf(v[d], v[d], s);
  s += __shfl_xor(s, 1, 64);
  s += __shfl_xor(s, 2, 64);
  if (kc4 == 0) csq[code] = s;
  _Float16 p1[16], p2[16];
#pragma unroll
  for (int d = 0; d < 16; ++d) split2h(v[d], p1[d], p2[d]);
  // 32-code group g, lane slot l; chunk (p,kc) holds 64 lanes x 8 f16:
  // lane (h*32+l) = code (g*32+l), k = kc*16 + h*8 + j.
  const int g = code >> 5, l = code & 31;
  _Float16* base = bSwz + (size_t)g * 4096;
#pragma unroll
  for (int p = 0; p < 2; ++p) {
    const _Float16* pl = p ? p2 : p1;
#pragma unroll
    for (int h = 0; h < 2; ++h) {
      h8v wv;
#pragma unroll
      for (int j = 0; j < 8; ++j) wv[j] = pl[h * 8 + j];
      *(h8v*)(base + (p * 4 + kc4) * 512 + (h * 32 + l) * 8) = wv;
    }
  }
}

__global__ __launch_bounds__(TPB, 2)
void vq_mfma_kernel(const float* __restrict__ x, const _Float16* __restrict__ bSwz,
                    const float* __restrict__ csq_g, int* __restrict__ out) {
  __shared__ alignas(16) _Float16 ldsBf[3 * BUF_HALFS];       // 99840 B
  __shared__ alignas(16) unsigned long long ldsRed[BROWS][4]; // 4096 B

  const int tid  = threadIdx.x;
  const int lane = tid & 63;
  const int w    = tid >> 6;
  const int cg   = w & 3;        // code group (32 codes)
  const int rh   = w >> 2;       // row half (64 rows = 2 stripes)
  const int half = lane >> 5;
  const int col  = lane & 31;
  const int wcode = cg * 32 + col;
  const int blockRow = blockIdx.x * BROWS;

  // ---- Issue tiles 0,1 DMA first (flies under the A-split VALU below).
#pragma unroll
  for (int tt = 0; tt < 2; ++tt) {
    const _Float16* gs = bSwz + (size_t)tt * TILE_HALFS + w * 512 + lane * 8;
    _Float16* ld = ldsBf + tt * BUF_HALFS + w * 512;
#pragma unroll
    for (int seg = 0; seg < 4; ++seg)
      gload_lds16(gs + seg * 4096, ld + seg * 4096);
    if (w < 2)
      gload_lds4(csq_g + tt * BTILE + w * 64 + lane,
                 (float*)(ldsBf + tt * BUF_HALFS + TILE_HALFS) + w * 64);
  }

  // ---- Stage A: split 128 x-rows into 2 f16 planes, XOR-swizzled, in the
  // buffer-2 region (transient; tile 2's DMA lands here only after the
  // afr-read fence below).
  _Float16* ldsA2 = ldsBf + 2 * BUF_HALFS;
  {
    const int row = tid >> 2, dseg = (tid & 3) * 16;
    const float* xp = x + (size_t)(blockRow + row) * DD + dseg;
    float v[16];
#pragma unroll
    for (int d = 0; d < 16; d += 4) {
      const float4 g = *(const float4*)(xp + d);
      v[d] = g.x; v[d + 1] = g.y; v[d + 2] = g.z; v[d + 3] = g.w;
    }
    _Float16 qa[16], qb[16];
#pragma unroll
    for (int e = 0; e < 16; ++e) split2h(v[e], qa[e], qb[e]);
#pragma unroll
    for (int h2 = 0; h2 < 2; ++h2) {
      h8v a, b;
#pragma unroll
      for (int j = 0; j < 8; ++j) { a[j] = qa[h2 * 8 + j]; b[j] = qb[h2 * 8 + j]; }
      const int slot = (tid & 3) * 2 + h2;           // 16B slot (d/8)
      *(h8v*)&ldsA2[((0 * BROWS + row) * 8 + (slot ^ (row & 7))) * 8] = a;
      *(h8v*)&ldsA2[((1 * BROWS + row) * 8 + (slot ^ (row & 7))) * 8] = b;
    }
  }
  // A-plane writes visible to all (lgkm only -- DMA stays in flight).
  asm volatile("s_waitcnt lgkmcnt(0)\n\ts_barrier" ::: "memory");

  // ---- A fragments resident: 2 stripes x 2 planes x 4 kchunks = 64 VGPR.
  h8v afr[2][2][4];
#pragma unroll
  for (int q = 0; q < 2; ++q)
#pragma unroll
    for (int p = 0; p < 2; ++p)
#pragma unroll
      for (int kc = 0; kc < 4; ++kc) {
        const int arow = rh * 64 + q * 32 + col;
        const int slot = kc * 2 + half;
        afr[q][p][kc] =
            *(const h8v*)&ldsA2[((p * BROWS + arow) * 8 + (slot ^ (arow & 7))) * 8];
      }
  // All afr reads done (lgkm) AND tile 0 resident (vmcnt<=4) before body 0.
  asm volatile("s_waitcnt vmcnt(4) lgkmcnt(0)\n\ts_barrier" ::: "memory");

  float bestD[32];
  unsigned bestC[32];
#pragma unroll
  for (int i = 0; i < 32; ++i) { bestD[i] = INFINITY; bestC[i] = 0u; }

  const f16v Z = {0.f,0.f,0.f,0.f,0.f,0.f,0.f,0.f,0.f,0.f,0.f,0.f,0.f,0.f,0.f,0.f};

  int buf = 0, pf = 2;
  for (int t = 0; t < NT; ++t) {
    // Prefetch tile t+2 into buf pf (4x16B per thread + csq by waves 0,1).
    if (t < NT - 2) {
      const _Float16* gs = bSwz + (size_t)(t + 2) * TILE_HALFS + w * 512 + lane * 8;
      _Float16* ld = ldsBf + pf * BUF_HALFS + w * 512;
#pragma unroll
      for (int seg = 0; seg < 4; ++seg)
        gload_lds16(gs + seg * 4096, ld + seg * 4096);
      if (w < 2)
        gload_lds4(csq_g + (t + 2) * BTILE + w * 64 + lane,
                   (float*)(ldsBf + pf * BUF_HALFS + TILE_HALFS) + w * 64);
    }
    // B fragments for this wave's code group: lane-linear b128, conflict-free.
    const _Float16* bp = ldsBf + buf * BUF_HALFS;
    const _Float16* rb = bp + cg * 4096 + lane * 8;
    h8v b0[4], b1[4];
#pragma unroll
    for (int kc = 0; kc < 4; ++kc) {
      b0[kc] = *(const h8v*)(rb + kc * 512);
      b1[kc] = *(const h8v*)(rb + (4 + kc) * 512);
    }
    const float cs = ((const float*)(bp + TILE_HALFS))[wcode];

    // 24 MFMAs: per stripe q, accA=h1g1 (4-chain), accB=h1g2'+h2'g1 (8-chain).
    f16v A0 = Z, B0 = Z, A1 = Z, B1 = Z;
#pragma unroll
    for (int kc = 0; kc < 4; ++kc) {
      A0 = __builtin_amdgcn_mfma_f32_32x32x16_f16(afr[0][0][kc], b0[kc], A0, 0, 0, 0);
      A1 = __builtin_amdgcn_mfma_f32_32x32x16_f16(afr[1][0][kc], b0[kc], A1, 0, 0, 0);
      B0 = __builtin_amdgcn_mfma_f32_32x32x16_f16(afr[0][0][kc], b1[kc], B0, 0, 0, 0);
      B1 = __builtin_amdgcn_mfma_f32_32x32x16_f16(afr[1][0][kc], b1[kc], B1, 0, 0, 0);
    }
#pragma unroll
    for (int kc = 0; kc < 4; ++kc) {
      B0 = __builtin_amdgcn_mfma_f32_32x32x16_f16(afr[0][1][kc], b0[kc], B0, 0, 0, 0);
      B1 = __builtin_amdgcn_mfma_f32_32x32x16_f16(afr[1][1][kc], b0[kc], B1, 0, 0, 0);
    }

    // Argmin epilogue (xsq dropped: per-row constant, argmin-invariant).
    const unsigned code = (unsigned)(t * BTILE) + wcode;
#pragma unroll
    for (int i = 0; i < 16; ++i) {
      const float d0 = fmaf(-2.f, fmaf(B0[i], 2.44140625e-4f, A0[i]), cs);
      if (d0 < bestD[i])      { bestD[i] = d0;      bestC[i] = code; }
      const float d1 = fmaf(-2.f, fmaf(B1[i], 2.44140625e-4f, A1[i]), cs);
      if (d1 < bestD[16 + i]) { bestD[16 + i] = d1; bestC[16 + i] = code; }
    }

    if (t < NT - 2)
      asm volatile("s_waitcnt vmcnt(4) lgkmcnt(0)\n\ts_barrier" ::: "memory");
    else if (t == NT - 2)
      asm volatile("s_waitcnt vmcnt(0) lgkmcnt(0)\n\ts_barrier" ::: "memory");
    buf = (buf == 2) ? 0 : buf + 1;
    pf  = (pf == 2) ? 0 : pf + 1;
  }

  // ---- Reduce across the 32 col-lanes, then across the 4 code-groups via
  // LDS. Keys use the monotone float-bit map (fkey) so unsigned u64 min ==
  // float min even for NEGATIVE dist surrogates; low 32 bits = code, so
  // exact ties resolve to the lowest code (numpy first-occurrence).
  unsigned long long key[32];
#pragma unroll
  for (int i = 0; i < 32; ++i)
    key[i] = ((unsigned long long)fkey(bestD[i]) << 32) | bestC[i];
#pragma unroll
  for (int i = 0; i < 32; ++i) {
#pragma unroll
    for (int m = 1; m < 32; m <<= 1) {
      const unsigned long long o = __shfl_xor(key[i], m, 64);
      if (o < key[i]) key[i] = o;
    }
  }
  if (col == 0) {
#pragma unroll
    for (int i = 0; i < 32; ++i) {
      const int ii = i & 15, q = i >> 4;
      const int row = rh * 64 + q * 32 + (ii & 3) + 8 * (ii >> 2) + 4 * half;
      ldsRed[row][cg] = key[i];
    }
  }
  __syncthreads();
  if (tid < BROWS) {
    unsigned long long a = ldsRed[tid][0];
    const unsigned long long b = ldsRed[tid][1];
    const unsigned long long c = ldsRed[tid][2];
    const unsigned long long d = ldsRed[tid][3];
    if (b < a) a = b;
    if (c < a) a = c;
    if (d < a) a = d;
    out[blockRow + tid] = (int)(unsigned)(a & 0xFFFFFFFFull);
  }
}

extern "C" void kernel_launch(void* const* d_in, const int* in_sizes, int n_in,
                              void* d_out, int out_size, void* d_ws, size_t ws_size,
                              hipStream_t stream) {
  const float* x  = (const float*)d_in[0];   // [N, 64] fp32
  const float* cb = (const float*)d_in[1];   // [K, 64] fp32
  int* out = (int*)d_out;                    // [N] int32

  // ws: bSwz (2 MB frag-ordered f16 planes) | csq (32 KB)
  _Float16* bSwz = (_Float16*)d_ws;
  float* csq_g = (float*)((char*)d_ws + (size_t)KC * DD * 2 * 2);

  vq_pre_kernel<<<dim3(KC * 4 / PTPB), dim3(PTPB), 0, stream>>>(cb, bSwz, csq_g);
  vq_mfma_kernel<<<dim3(NROWS / BROWS), dim3(TPB), 0, stream>>>(
      x, bSwz, csq_g, out);
}

// Round 6
// 177.625 us; speedup vs baseline: 1.0183x; 1.0183x over previous
//
#include <hip/hip_runtime.h>
#include <math.h>

// VectorQuantizer: argmin_k ||x_n - c_k||^2, N=32768, K=8192, D=64, fp32.
// Round-12: 2 independent blocks/CU + 2-stripe B-reuse + one-late epilogue.
//
// Counter model learned r11: VALUBusy INCLUDES MfmaUtil (r11 gap 3.8% ==
// computed pure-VALU). Rounds 7-11 all sit at the ~30% "2-phase ceiling"
// (m233): monolithic read->MFMA->epilogue->barrier bodies. Fixes here:
//  * 2 blocks/CU (512 blocks, 68.6KB LDS each): independent barrier groups
//    slip against each other -> one block's MFMAs fill the other's stalls.
//    (r8 had this at 124.8us; r9/r11's 1-block lockstep lost it.)
//  * 2-stripe waves (r9/r11's one valid gain): wave = 64 rows x 32 codes,
//    24 MFMA per 8 ds_read_b128 -> per-CU LDS reads (770cy) << MFMA (1550cy).
//  * T15-lite epilogue: argmin compare for tile t-1 runs in body t against
//    foldP[32] (one fmaf/slot fold is the only same-tile acc use). foldP
//    primed -INF => tile-0 epilogue is a branchless no-op (d=+inf).
//  * Double-buffer, prefetch at body TOP (8x gload_lds16 + 2x gload_lds4
//    csq by wave 0), vmcnt(0) drain at the end barrier is covered by the
//    ~2000cy body. setprio(1) around the MFMA cluster (cross-block role
//    diversity exists).
// Numerics identical to rounds 7-11 (passed, absmax 0): 2-plane f16 split
// (plane1 denormal-zeroed, plane2 pre-scaled 2^12), 3 products (accA=h1g1
// 4-chain, accB=h1g2'+h2'g1 8-chain), d = fmaf(-2, fmaf(accB,2^-12,accA),
// csq) [xsq omitted: per-row constant, argmin-invariant], strict < ascending
// code, fkey-mapped u64 mins (handles negative d) = first-occurrence.
// C/D layout (measured m74/m101): col=lane&31, row=(reg&3)+8*(reg>>2)+4*(lane>>5).

typedef __attribute__((ext_vector_type(8)))  _Float16 h8v;
typedef __attribute__((ext_vector_type(16))) float f16v;

constexpr int NROWS = 32768;
constexpr int KC    = 8192;
constexpr int DD    = 64;
constexpr int TPB   = 256;                 // 4 waves, one 32-code group each
constexpr int PTPB  = 256;                 // pre-kernel block size
constexpr int BROWS = 64;                  // rows per block -> 512 blocks = 2/CU
constexpr int BTILE = 128;                 // codes per tile (4 x 32-code groups)
constexpr int NT    = KC / BTILE;          // 64 tiles
constexpr int TILE_HALFS = BTILE * DD * 2;     // 16384 halves = 32 KB per tile
constexpr int BUF_HALFS  = TILE_HALFS + 256;   // + 128-float csq slot (512 B)

__device__ __forceinline__ void split2h(float v, _Float16& h1, _Float16& h2) {
  const float av = fabsf(v);
  _Float16 a = (_Float16)v;                  // RNE
  if (av < 6.1035156e-5f) a = (_Float16)0.f; // keep plane-1 out of f16 denormals
  h1 = a;
  h2 = (_Float16)((v - (float)a) * 4096.f);  // exact residual, scaled 2^12
}

__device__ __forceinline__ void gload_lds16(const void* g, void* l) {
  __builtin_amdgcn_global_load_lds(
      (const __attribute__((address_space(1))) void*)g,
      (__attribute__((address_space(3))) void*)l, 16, 0, 0);
}
__device__ __forceinline__ void gload_lds4(const void* g, void* l) {
  __builtin_amdgcn_global_load_lds(
      (const __attribute__((address_space(1))) void*)g,
      (__attribute__((address_space(3))) void*)l, 4, 0, 0);
}

// Monotone map: unsigned order of mapped bits == float order (handles negatives).
__device__ __forceinline__ unsigned fkey(float f) {
  const unsigned u = __float_as_uint(f);
  return u ^ (((unsigned)((int)u >> 31)) | 0x80000000u);
}

// Pre-kernel (128 blocks, 4 threads/code): split cb -> frag-ordered bSwz
// (2 f16 planes) + csq. Unchanged from rounds 9-11 (passed).
__global__ void vq_pre_kernel(const float* __restrict__ cb,
                              _Float16* __restrict__ bSwz,
                              float* __restrict__ csq) {
  const int gidx = blockIdx.x * PTPB + threadIdx.x;  // 0..32767
  const int code = gidx >> 2;
  const int kc4  = gidx & 3;                         // this thread's k-chunk
  const float* cp = cb + (size_t)code * DD + kc4 * 16;
  float v[16];
#pragma unroll
  for (int d = 0; d < 16; d += 4) {
    const float4 g = *(const float4*)(cp + d);
    v[d] = g.x; v[d + 1] = g.y; v[d + 2] = g.z; v[d + 3] = g.w;
  }
  float s = 0.f;
#pragma unroll
  for (int d = 0; d < 16; ++d) s = fmaf(v[d], v[d], s);
  s += __shfl_xor(s, 1, 64);
  s += __shfl_xor(s, 2, 64);
  if (kc4 == 0) csq[code] = s;
  _Float16 p1[16], p2[16];
#pragma unroll
  for (int d = 0; d < 16; ++d) split2h(v[d], p1[d], p2[d]);
  // 32-code group g, lane slot l; chunk (p,kc) holds 64 lanes x 8 f16:
  // lane (h*32+l) = code (g*32+l), k = kc*16 + h*8 + j.
  const int g = code >> 5, l = code & 31;
  _Float16* base = bSwz + (size_t)g * 4096;
#pragma unroll
  for (int p = 0; p < 2; ++p) {
    const _Float16* pl = p ? p2 : p1;
#pragma unroll
    for (int h = 0; h < 2; ++h) {
      h8v wv;
#pragma unroll
      for (int j = 0; j < 8; ++j) wv[j] = pl[h * 8 + j];
      *(h8v*)(base + (p * 4 + kc4) * 512 + (h * 32 + l) * 8) = wv;
    }
  }
}

__global__ __launch_bounds__(TPB, 2)
void vq_mfma_kernel(const float* __restrict__ x, const _Float16* __restrict__ bSwz,
                    const float* __restrict__ csq_g, int* __restrict__ out) {
  __shared__ alignas(16) _Float16 ldsBf[2 * BUF_HALFS];       // 66560 B
  __shared__ alignas(16) unsigned long long ldsRed[BROWS][4]; // 2048 B

  const int tid  = threadIdx.x;
  const int lane = tid & 63;
  const int w    = tid >> 6;     // wave = code group (32 codes)
  const int half = lane >> 5;
  const int col  = lane & 31;
  const int wcode = w * 32 + col;
  const int blockRow = blockIdx.x * BROWS;

  // ---- Issue tile 0 DMA first (flies under the A-split VALU below).
  {
    const _Float16* gs = bSwz + tid * 8;
    _Float16* ld = ldsBf + tid * 8;
#pragma unroll
    for (int seg = 0; seg < 8; ++seg)
      gload_lds16(gs + seg * 2048, ld + seg * 2048);
    if (w == 0) {
      float* cslot = (float*)(ldsBf + TILE_HALFS);
      gload_lds4(csq_g + lane, cslot);
      gload_lds4(csq_g + 64 + lane, cslot + 64);
    }
  }

  // ---- Stage A: split 64 x-rows into 2 f16 planes, XOR-swizzled, in the
  // buffer-1 region (transient; tile 1's DMA lands here only after the
  // afr-read fence below).
  _Float16* ldsA = ldsBf + BUF_HALFS;
  {
    const int row = tid >> 2, dseg = (tid & 3) * 16;
    const float* xp = x + (size_t)(blockRow + row) * DD + dseg;
    float v[16];
#pragma unroll
    for (int d = 0; d < 16; d += 4) {
      const float4 g = *(const float4*)(xp + d);
      v[d] = g.x; v[d + 1] = g.y; v[d + 2] = g.z; v[d + 3] = g.w;
    }
    _Float16 qa[16], qb[16];
#pragma unroll
    for (int e = 0; e < 16; ++e) split2h(v[e], qa[e], qb[e]);
#pragma unroll
    for (int h2 = 0; h2 < 2; ++h2) {
      h8v a, b;
#pragma unroll
      for (int j = 0; j < 8; ++j) { a[j] = qa[h2 * 8 + j]; b[j] = qb[h2 * 8 + j]; }
      const int slot = (tid & 3) * 2 + h2;           // 16B slot (d/8)
      *(h8v*)&ldsA[(0 * 64 + row) * 64 + (slot ^ (row & 7)) * 8] = a;
      *(h8v*)&ldsA[(1 * 64 + row) * 64 + (slot ^ (row & 7)) * 8] = b;
    }
  }
  // A-plane writes visible to all (lgkm only -- DMA stays in flight).
  asm volatile("s_waitcnt lgkmcnt(0)\n\ts_barrier" ::: "memory");

  // ---- A fragments resident: 2 stripes x 2 planes x 4 kchunks = 64 VGPR.
  h8v afr[2][2][4];
#pragma unroll
  for (int q = 0; q < 2; ++q)
#pragma unroll
    for (int p = 0; p < 2; ++p)
#pragma unroll
      for (int kc = 0; kc < 4; ++kc) {
        const int arow = q * 32 + col;
        const int slot = kc * 2 + half;
        afr[q][p][kc] =
            *(const h8v*)&ldsA[(p * 64 + arow) * 64 + ((slot ^ (arow & 7))) * 8];
      }
  // afr reads done (lgkm) AND tile 0 resident (vmcnt 0) before body 0
  // (which DMAs tile 1 into the A region).
  asm volatile("s_waitcnt vmcnt(0) lgkmcnt(0)\n\ts_barrier" ::: "memory");

  float bestD[32];
  unsigned bestC[32];
  float foldP[32];
#pragma unroll
  for (int i = 0; i < 32; ++i) {
    bestD[i] = INFINITY; bestC[i] = 0u; foldP[i] = -INFINITY;  // d=+inf at t=0
  }
  float csP = 0.f;
  unsigned codeP = 0u;

  const f16v Z = {0.f,0.f,0.f,0.f,0.f,0.f,0.f,0.f,0.f,0.f,0.f,0.f,0.f,0.f,0.f,0.f};

#pragma unroll 2
  for (int t = 0; t < NT; ++t) {
    const int buf = t & 1;
    const _Float16* bp = ldsBf + buf * BUF_HALFS;
    // Prefetch tile t+1 into the other buffer (issued at body TOP; the
    // body's ~2000cy of compute covers L2 latency before the drain).
    if (t + 1 < NT) {
      const _Float16* gs = bSwz + (size_t)(t + 1) * TILE_HALFS + tid * 8;
      _Float16* ld = ldsBf + (buf ^ 1) * BUF_HALFS + tid * 8;
#pragma unroll
      for (int seg = 0; seg < 8; ++seg)
        gload_lds16(gs + seg * 2048, ld + seg * 2048);
      if (w == 0) {
        float* cslot = (float*)(ldsBf + (buf ^ 1) * BUF_HALFS + TILE_HALFS);
        gload_lds4(csq_g + (t + 1) * BTILE + lane, cslot);
        gload_lds4(csq_g + (t + 1) * BTILE + 64 + lane, cslot + 64);
      }
    }
    // B fragments for this wave's code group: lane-linear b128, conflict-free.
    const _Float16* rb = bp + w * 4096 + lane * 8;
    h8v b0[4], b1[4];
#pragma unroll
    for (int kc = 0; kc < 4; ++kc) {
      b0[kc] = *(const h8v*)(rb + kc * 512);
      b1[kc] = *(const h8v*)(rb + (4 + kc) * 512);
    }
    const float cs = ((const float*)(bp + TILE_HALFS))[wcode];

    // 24 MFMAs: per stripe q, accA=h1g1 (4-chain), accB=h1g2'+h2'g1 (8-chain).
    __builtin_amdgcn_s_setprio(1);
    f16v A0 = Z, B0v = Z, A1 = Z, B1v = Z;
#pragma unroll
    for (int kc = 0; kc < 4; ++kc) {
      A0  = __builtin_amdgcn_mfma_f32_32x32x16_f16(afr[0][0][kc], b0[kc], A0,  0, 0, 0);
      A1  = __builtin_amdgcn_mfma_f32_32x32x16_f16(afr[1][0][kc], b0[kc], A1,  0, 0, 0);
      B0v = __builtin_amdgcn_mfma_f32_32x32x16_f16(afr[0][0][kc], b1[kc], B0v, 0, 0, 0);
      B1v = __builtin_amdgcn_mfma_f32_32x32x16_f16(afr[1][0][kc], b1[kc], B1v, 0, 0, 0);
    }
#pragma unroll
    for (int kc = 0; kc < 4; ++kc) {
      B0v = __builtin_amdgcn_mfma_f32_32x32x16_f16(afr[0][1][kc], b0[kc], B0v, 0, 0, 0);
      B1v = __builtin_amdgcn_mfma_f32_32x32x16_f16(afr[1][1][kc], b0[kc], B1v, 0, 0, 0);
    }
    __builtin_amdgcn_s_setprio(0);

    // Epilogue for tile t-1 (reads foldP/csP/codeP: long-completed VALU data,
    // no dependency on this tile's in-flight MFMA chains).
#pragma unroll
    for (int i = 0; i < 32; ++i) {
      const float d_ = fmaf(-2.f, foldP[i], csP);
      if (d_ < bestD[i]) { bestD[i] = d_; bestC[i] = codeP; }
    }
    // Fold tile t (the only same-tile acc use: one fmaf per slot).
#pragma unroll
    for (int i = 0; i < 16; ++i) {
      foldP[i]      = fmaf(B0v[i], 2.44140625e-4f, A0[i]);
      foldP[16 + i] = fmaf(B1v[i], 2.44140625e-4f, A1[i]);
    }
    csP = cs;
    codeP = (unsigned)(t * BTILE) + wcode;

    asm volatile("s_waitcnt vmcnt(0) lgkmcnt(0)\n\ts_barrier" ::: "memory");
  }
  // Final epilogue: tile NT-1.
#pragma unroll
  for (int i = 0; i < 32; ++i) {
    const float d_ = fmaf(-2.f, foldP[i], csP);
    if (d_ < bestD[i]) { bestD[i] = d_; bestC[i] = codeP; }
  }

  // ---- Reduce across the 32 col-lanes (fkey-mapped u64 min keeps float
  // order incl. negatives; lowest code on exact ties), then across the 4
  // code-groups via LDS.
  unsigned long long key[32];
#pragma unroll
  for (int i = 0; i < 32; ++i)
    key[i] = ((unsigned long long)fkey(bestD[i]) << 32) | bestC[i];
#pragma unroll
  for (int i = 0; i < 32; ++i) {
#pragma unroll
    for (int m = 1; m < 32; m <<= 1) {
      const unsigned long long o = __shfl_xor(key[i], m, 64);
      if (o < key[i]) key[i] = o;
    }
  }
  if (col == 0) {
#pragma unroll
    for (int i = 0; i < 32; ++i) {
      const int ii = i & 15, q = i >> 4;
      const int row = q * 32 + (ii & 3) + 8 * (ii >> 2) + 4 * half;
      ldsRed[row][w] = key[i];
    }
  }
  __syncthreads();
  if (tid < BROWS) {
    unsigned long long a = ldsRed[tid][0];
    const unsigned long long b = ldsRed[tid][1];
    const unsigned long long c = ldsRed[tid][2];
    const unsigned long long d = ldsRed[tid][3];
    if (b < a) a = b;
    if (c < a) a = c;
    if (d < a) a = d;
    out[blockRow + tid] = (int)(unsigned)(a & 0xFFFFFFFFull);
  }
}

extern "C" void kernel_launch(void* const* d_in, const int* in_sizes, int n_in,
                              void* d_out, int out_size, void* d_ws, size_t ws_size,
                              hipStream_t stream) {
  const float* x  = (const float*)d_in[0];   // [N, 64] fp32
  const float* cb = (const float*)d_in[1];   // [K, 64] fp32
  int* out = (int*)d_out;                    // [N] int32

  // ws: bSwz (2 MB frag-ordered f16 planes) | csq (32 KB)
  _Float16* bSwz = (_Float16*)d_ws;
  float* csq_g = (float*)((char*)d_ws + (size_t)KC * DD * 2 * 2);

  vq_pre_kernel<<<dim3(KC * 4 / PTPB), dim3(PTPB), 0, stream>>>(cb, bSwz, csq_g);
  vq_mfma_kernel<<<dim3(NROWS / BROWS), dim3(TPB), 0, stream>>>(
      x, bSwz, csq_g, out);
}